// Round 8
// baseline (416.051 us; speedup 1.0000x reference)
//
#include <hip/hip_runtime.h>
#include <hip/hip_bf16.h>
#include <stdint.h>

// non_local_layer: B=8, C=1024, N=48*48=2304, Cb=512. f32 in/out, bf16 MFMA inside.
// R16: two counter-verified fixes to R15.
// (1) tr stride 128 -> 140 (LDS 35840). Stride 128 = 64 words = 0 mod 32 banks ->
//     16-way write conflicts + all-bank-0 mirror reads; 5.80M conflict-cycles / 256 CU
//     = 9.4us = the observed +11us. Stride 140 (35 words, odd) was the R13 zero-
//     conflict config. Lesson: R11's "conflicts don't matter" compared 136 vs 140 --
//     both conflict-free-ish on the read side; 128 is the pathological case.
// (2) softmax normalization moved from y-GEMM A-STAGING (24 VALU/chunk on the staging
//     critical path, ~768 ops/thread total) to the y-GEMM EPILOGUE (per-output-row
//     scale commutes out of the K-loop: 16 divides/thread once per block). Also more
//     accurate: no bf16 re-quantization of scaled A.

typedef __bf16 bf16;
typedef __attribute__((ext_vector_type(8))) __bf16 bf16x8;
typedef __attribute__((ext_vector_type(4))) __bf16 bf16x4;
typedef __attribute__((ext_vector_type(4))) float f32x4;

// ---------------- GEMM: 128x128 tile, BK=64, 4 waves x (4x4) 16x16x32 MFMA ----------------
// bt-form: D[m][n] = sum_k A[m][k]*B[n][k]; per-z strides sA/sB/sD; D ld=N; alpha scale.
// 1-D grid with z-major XCD affinity: d = blockIdx.x; zz = d % nz; t = d / nz.
// SMAX: scale output row m by 1/rsum[m] in the EPILOGUE (fused softmax normalization).
// BNRED: accumulate sum/sumsq of D over columns per row (channel) into ps/pq.
template <bool F32OUT, bool BNRED, bool BXI, bool SMAX>
__global__ __launch_bounds__(256)
void gemm_btz(const bf16* __restrict__ Ag, const bf16* __restrict__ Bg,
              void* __restrict__ Dg, int K, int N,
              long long sA, long long sB, long long sD, float alpha,
              float* __restrict__ ps, float* __restrict__ pq,
              const float* __restrict__ rsum, long long sR, int nInner, int nz)
{
    const int d  = blockIdx.x;
    const int zz = d % nz;
    const int t0 = d / nz;
    const int bI = t0 % nInner;
    const int bO = t0 / nInner;
    const int bx = BXI ? bI : bO;
    const int by = BXI ? bO : bI;

    __shared__ char lds[32768];            // A tile 16 KB + B tile 16 KB
    char* ldsA = lds;
    char* ldsB = lds + 16384;

    const int lane = threadIdx.x & 63;
    const int wv   = threadIdx.x >> 6;     // 4 waves, 2x2 arrangement
    const int wm   = wv >> 1;
    const int wn   = wv & 1;

    const bf16* Ab = Ag + (long long)zz * sA + (long long)by * 128 * K;
    const bf16* Bb = Bg + (long long)zz * sB + (long long)bx * 128 * K;

    f32x4 acc[4][4];
    #pragma unroll
    for (int i = 0; i < 4; ++i)
        #pragma unroll
        for (int j = 0; j < 4; ++j) {
            f32x4 z = {0.f, 0.f, 0.f, 0.f};
            acc[i][j] = z;
        }

    for (int k0 = 0; k0 < K; k0 += 64) {
        #pragma unroll
        for (int t = 0; t < 4; ++t) {
            int ch  = (wv * 4 + t) * 64 + lane;   // 0..1023
            int row = ch >> 3;
            int cc  = (ch & 7) ^ (row & 7);
            bf16x8 va = *(const bf16x8*)(Ab + (long long)row * K + k0 + cc * 8);
            bf16x8 vb = *(const bf16x8*)(Bb + (long long)row * K + k0 + cc * 8);
            *(bf16x8*)(ldsA + ch * 16) = va;
            *(bf16x8*)(ldsB + ch * 16) = vb;
        }
        __syncthreads();

        #pragma unroll
        for (int kk = 0; kk < 64; kk += 32) {
            bf16x8 af[4], bfr[4];
            #pragma unroll
            for (int i = 0; i < 4; ++i) {
                int r = wm * 64 + i * 16 + (lane & 15);
                int c = ((kk >> 3) + (lane >> 4)) ^ (r & 7);
                af[i] = *(const bf16x8*)(ldsA + r * 128 + c * 16);
            }
            #pragma unroll
            for (int j = 0; j < 4; ++j) {
                int r = wn * 64 + j * 16 + (lane & 15);
                int c = ((kk >> 3) + (lane >> 4)) ^ (r & 7);
                bfr[j] = *(const bf16x8*)(ldsB + r * 128 + c * 16);
            }
            #pragma unroll
            for (int i = 0; i < 4; ++i)
                #pragma unroll
                for (int j = 0; j < 4; ++j)
                    acc[i][j] = __builtin_amdgcn_mfma_f32_16x16x32_bf16(af[i], bfr[j], acc[i][j], 0, 0, 0);
        }
        __syncthreads();
    }

    float* bs = (float*)lds;               // [128] per-channel sum
    float* bq = (float*)(lds + 512);       // [128] per-channel sumsq
    if (BNRED) {
        if (threadIdx.x < 128) { bs[threadIdx.x] = 0.f; bq[threadIdx.x] = 0.f; }
        __syncthreads();
    }

    const int m_base = by * 128 + wm * 64;
    const int n_base = bx * 128 + wn * 64;

    // fused softmax normalization: per-output-row scale, computed once per block
    float sca[4][4];
    #pragma unroll
    for (int i = 0; i < 4; ++i)
        #pragma unroll
        for (int t = 0; t < 4; ++t) {
            if (SMAX)
                sca[i][t] = alpha / rsum[(long long)zz * sR + m_base + i * 16 + (lane >> 4) * 4 + t];
            else
                sca[i][t] = alpha;
        }

    float s_it[4][4], q_it[4][4];
    #pragma unroll
    for (int i = 0; i < 4; ++i) {
        #pragma unroll
        for (int t = 0; t < 4; ++t) { s_it[i][t] = 0.f; q_it[i][t] = 0.f; }
    }
    #pragma unroll
    for (int i = 0; i < 4; ++i) {
        #pragma unroll
        for (int j = 0; j < 4; ++j) {
            int col = n_base + j * 16 + (lane & 15);
            #pragma unroll
            for (int t = 0; t < 4; ++t) {
                int rowg = m_base + i * 16 + (lane >> 4) * 4 + t;
                float v = acc[i][j][t] * sca[i][t];
                if (F32OUT) ((float*)Dg)[(long long)zz * sD + (long long)rowg * N + col] = v;
                else        ((bf16*)Dg)[(long long)zz * sD + (long long)rowg * N + col] = (bf16)v;
                if (BNRED) { s_it[i][t] += v; q_it[i][t] += v * v; }
            }
        }
    }

    if (BNRED) {
        #pragma unroll
        for (int i = 0; i < 4; ++i) {
            #pragma unroll
            for (int t = 0; t < 4; ++t) {
                float s = s_it[i][t], q = q_it[i][t];
                #pragma unroll
                for (int m = 1; m < 16; m <<= 1) {
                    s += __shfl_xor(s, m);
                    q += __shfl_xor(q, m);
                }
                if ((lane & 15) == 0) {
                    int cl = wm * 64 + i * 16 + (lane >> 4) * 4 + t;   // 0..127
                    atomicAdd(&bs[cl], s);
                    atomicAdd(&bq[cl], q);
                }
            }
        }
        __syncthreads();
        if (threadIdx.x < 128) {
            int cg = by * 128 + threadIdx.x;
            atomicAdd(&ps[cg], bs[threadIdx.x]);
            atomicAdd(&pq[cg], bq[threadIdx.x]);
        }
    }
}

// ---------------- symmetric GEMM: D = exp(alpha * X X^T), upper-tri + sum-of-exp ----------------
// Compact triangular launch with z-major XCD affinity (R12). Stores UNNORMALIZED
// exp(S) (max-free: |S*alpha| <= ~0.5 here) and accumulates per-row sum-of-exp into
// rsum[z][row] via shfl-reduce + atomicAdd. Off-diagonal tiles also mirror the tile
// via LDS transpose (stride 140 = 35 words: odd -> conflict-free, R13-proven) and
// contribute their COLUMN sums to the mirrored rows (exactly-once row coverage).
__global__ __launch_bounds__(256)
void gemm_sym(const bf16* __restrict__ Xg, bf16* __restrict__ Dg,
              int K, int N, long long sX, long long sD, float alpha,
              float* __restrict__ rsum)
{
    const int NZ = gridDim.z;
    const int d  = blockIdx.z * 171 + blockIdx.x;
    const int zz = d % NZ;
    int tlin     = d / NZ;                 // 0..170, bijective (171*NZ blocks total)
    int bi = 0;
    while (tlin >= 18 - bi) { tlin -= 18 - bi; ++bi; }
    const int bj = bi + tlin;
    const bool mir  = (bj > bi);
    const bool diag = (bj == bi);

    __shared__ __align__(16) char lds[35840];   // GEMM: A 16K + B 16K; epilogue: 128 x 140 bf16
    char* ldsA = lds;
    char* ldsB = diag ? lds : (lds + 16384);

    const int lane = threadIdx.x & 63;
    const int wv   = threadIdx.x >> 6;
    const int wm   = wv >> 1;
    const int wn   = wv & 1;

    const bf16* Ab = Xg + (long long)zz * sX + (long long)bi * 128 * K;
    const bf16* Bb = Xg + (long long)zz * sX + (long long)bj * 128 * K;

    f32x4 acc[4][4];
    #pragma unroll
    for (int i = 0; i < 4; ++i)
        #pragma unroll
        for (int j = 0; j < 4; ++j) {
            f32x4 z = {0.f, 0.f, 0.f, 0.f};
            acc[i][j] = z;
        }

    for (int k0 = 0; k0 < K; k0 += 64) {
        #pragma unroll
        for (int t = 0; t < 4; ++t) {
            int ch  = (wv * 4 + t) * 64 + lane;   // 0..1023
            int row = ch >> 3;
            int cc  = (ch & 7) ^ (row & 7);
            bf16x8 va = *(const bf16x8*)(Ab + (long long)row * K + k0 + cc * 8);
            *(bf16x8*)(ldsA + ch * 16) = va;
            if (!diag) {
                bf16x8 vb = *(const bf16x8*)(Bb + (long long)row * K + k0 + cc * 8);
                *(bf16x8*)(ldsB + ch * 16) = vb;
            }
        }
        __syncthreads();

        #pragma unroll
        for (int kk = 0; kk < 64; kk += 32) {
            bf16x8 af[4], bfr[4];
            #pragma unroll
            for (int i = 0; i < 4; ++i) {
                int r = wm * 64 + i * 16 + (lane & 15);
                int c = ((kk >> 3) + (lane >> 4)) ^ (r & 7);
                af[i] = *(const bf16x8*)(ldsA + r * 128 + c * 16);
            }
            #pragma unroll
            for (int j = 0; j < 4; ++j) {
                int r = wn * 64 + j * 16 + (lane & 15);
                int c = ((kk >> 3) + (lane >> 4)) ^ (r & 7);
                bfr[j] = *(const bf16x8*)(ldsB + r * 128 + c * 16);
            }
            #pragma unroll
            for (int i = 0; i < 4; ++i)
                #pragma unroll
                for (int j = 0; j < 4; ++j)
                    acc[i][j] = __builtin_amdgcn_mfma_f32_16x16x32_bf16(af[i], bfr[j], acc[i][j], 0, 0, 0);
        }
        __syncthreads();
    }

    bf16* Db = Dg + (long long)zz * sD;
    float* rs = rsum + (long long)zz * N;
    bf16 (*tr)[140] = (bf16(*)[140])lds;   // k-loop ended with a barrier; LDS free

    float rowsum[4][4];
    float colsum[4];
    #pragma unroll
    for (int i = 0; i < 4; ++i)
        #pragma unroll
        for (int t = 0; t < 4; ++t) rowsum[i][t] = 0.f;
    #pragma unroll
    for (int j = 0; j < 4; ++j) colsum[j] = 0.f;

    #pragma unroll
    for (int i = 0; i < 4; ++i) {
        #pragma unroll
        for (int j = 0; j < 4; ++j) {
            int c_loc = wn * 64 + j * 16 + (lane & 15);
            int col   = bj * 128 + c_loc;
            bf16x4 tv;
            #pragma unroll
            for (int t = 0; t < 4; ++t) {
                int r_loc = wm * 64 + i * 16 + (lane >> 4) * 4 + t;
                float e = __expf(acc[i][j][t] * alpha);
                bf16 eb = (bf16)e;
                Db[(long long)(bi * 128 + r_loc) * N + col] = eb;
                tv[t] = eb;
                rowsum[i][t] += e;
                colsum[j]    += e;
            }
            if (mir) {
                int r_base = wm * 64 + i * 16 + (lane >> 4) * 4;   // 8B-aligned in tr row
                *(bf16x4*)(&tr[c_loc][r_base]) = tv;               // one ds_write_b64
            }
        }
    }

    // row sums: reduce across the 16 col-lanes, one atomicAdd per row
    #pragma unroll
    for (int i = 0; i < 4; ++i) {
        #pragma unroll
        for (int t = 0; t < 4; ++t) {
            float s = rowsum[i][t];
            s += __shfl_xor(s, 1); s += __shfl_xor(s, 2);
            s += __shfl_xor(s, 4); s += __shfl_xor(s, 8);
            if ((lane & 15) == 0)
                atomicAdd(&rs[bi * 128 + wm * 64 + i * 16 + (lane >> 4) * 4 + t], s);
        }
    }
    // col sums -> mirrored rows (off-diagonal only): reduce across the 4 row-lane-groups
    if (mir) {
        #pragma unroll
        for (int j = 0; j < 4; ++j) {
            float s = colsum[j];
            s += __shfl_xor(s, 16); s += __shfl_xor(s, 32);
            if (lane < 16)
                atomicAdd(&rs[bj * 128 + wn * 64 + j * 16 + lane], s);
        }
        __syncthreads();
        // 256 threads x 64 bf16: thread (cc=tid>>1, hf=tid&1) copies half a transposed row.
        const int cc = threadIdx.x >> 1, hf = threadIdx.x & 1;
        const bf16* src = &tr[cc][hf * 64];
        bf16* dst = Db + (long long)(bj * 128 + cc) * N + bi * 128 + hf * 64;
        #pragma unroll
        for (int j2 = 0; j2 < 8; ++j2)
            *(bf16x8*)(dst + j2 * 8) = *(const bf16x8*)(src + j2 * 8);
    }
}

// ---------------- f32 -> bf16 bulk convert (weights) ----------------
__global__ __launch_bounds__(256)
void f32_to_bf16(const float* __restrict__ in, bf16* __restrict__ out, int n)
{
    int idx = (blockIdx.x * 256 + threadIdx.x) * 4;
    if (idx < n) {
        float4 v = *(const float4*)(in + idx);
        out[idx + 0] = (bf16)v.x;
        out[idx + 1] = (bf16)v.y;
        out[idx + 2] = (bf16)v.z;
        out[idx + 3] = (bf16)v.w;
    }
}

// ---------------- zero-init f32 accumulators (ws is poisoned 0xAA every launch) ----------------
__global__ __launch_bounds__(256)
void zero_f32(float* __restrict__ p)
{
    p[blockIdx.x * 256 + threadIdx.x] = 0.f;
}

// ---------------- batched transpose x[z][C][N] (f32) -> xT[z][N][C] (bf16) ----------------
__global__ __launch_bounds__(256)
void transpose_f32_bf16(const float* __restrict__ x, bf16* __restrict__ xT)
{
    __shared__ bf16 tile[32][33];
    const float* xb = x + (long long)blockIdx.z * 1024 * 2304;
    bf16* xo = xT + (long long)blockIdx.z * 2304 * 1024;
    const int n0 = blockIdx.x * 32;
    const int c0 = blockIdx.y * 32;
    const int tx = threadIdx.x, ty = threadIdx.y;   // (32, 8)
    #pragma unroll
    for (int i = 0; i < 32; i += 8)
        tile[ty + i][tx] = (bf16)xb[(long long)(c0 + ty + i) * 2304 + n0 + tx];
    __syncthreads();
    #pragma unroll
    for (int i = 0; i < 32; i += 8)
        xo[(long long)(n0 + ty + i) * 1024 + c0 + tx] = tile[tx][ty + i];
}

// ---------------- BN finalize: psum/pqsm already summed over all batches ----------------
__global__ __launch_bounds__(256)
void bn_finalize(const float* __restrict__ ps, const float* __restrict__ pq,
                 float* __restrict__ mean, float* __restrict__ istd)
{
    int c = blockIdx.x * 256 + threadIdx.x;   // grid 4 x 256 = 1024
    float mu = ps[c] / 18432.0f;
    mean[c] = mu;
    istd[c] = rsqrtf(pq[c] / 18432.0f - mu * mu + 1e-5f);
}

// ---------------- BN apply + residual: wy in bf16, x/z f32 ----------------
__global__ __launch_bounds__(256)
void bn_apply_b(const bf16* __restrict__ wy, const float* __restrict__ x,
                const float* __restrict__ gamma, const float* __restrict__ beta,
                const float* __restrict__ mean, const float* __restrict__ istd,
                float* __restrict__ z)
{
    long long idx = ((long long)blockIdx.x * 256 + threadIdx.x) * 8;
    int c = (int)((idx / 2304) & 1023);    // layout [B][C][N], N divisible by 8
    float sc = gamma[c] * istd[c];
    float sh = beta[c] - mean[c] * sc;
    bf16x8 w  = *(const bf16x8*)(wy + idx);
    float4 x0 = *(const float4*)(x + idx);
    float4 x1 = *(const float4*)(x + idx + 4);
    float4 o0, o1;
    o0.x = (float)w[0] * sc + sh + x0.x;
    o0.y = (float)w[1] * sc + sh + x0.y;
    o0.z = (float)w[2] * sc + sh + x0.z;
    o0.w = (float)w[3] * sc + sh + x0.w;
    o1.x = (float)w[4] * sc + sh + x1.x;
    o1.y = (float)w[5] * sc + sh + x1.y;
    o1.z = (float)w[6] * sc + sh + x1.z;
    o1.w = (float)w[7] * sc + sh + x1.w;
    *(float4*)(z + idx)     = o0;
    *(float4*)(z + idx + 4) = o1;
}

extern "C" void kernel_launch(void* const* d_in, const int* in_sizes, int n_in,
                              void* d_out, int out_size, void* d_ws, size_t ws_size,
                              hipStream_t stream)
{
    const float* x     = (const float*)d_in[0];
    const float* Wg    = (const float*)d_in[1];
    const float* Wz    = (const float*)d_in[2];
    const float* gamma = (const float*)d_in[3];
    const float* beta  = (const float*)d_in[4];
    float* zo = (float*)d_out;

    const int B = 8, C = 1024, Cb = 512, N = 2304;

    // ws-adaptive batch chunking: BC in {8,4,2,1}, largest whose footprint fits.
    const size_t fixedB = ((size_t)Cb * C * 2) * 2 + (size_t)C * 4 * 4 + 4096;
    const size_t perB   = ((size_t)N * C + (size_t)Cb * N + (size_t)N * N + (size_t)N * Cb
                           + (size_t)C * N) * 2 + (size_t)N * 4 + 1536;
    int BC = 8;
    while (BC > 1 && fixedB + perB * (size_t)BC > ws_size) BC >>= 1;

    char* p = (char*)d_ws;
    auto alloc = [&](size_t bytes) { char* r = p; p += (bytes + 255) & ~(size_t)255; return r; };
    bf16*  Wgb  = (bf16*)alloc((size_t)Cb * C * 2);
    bf16*  Wzb  = (bf16*)alloc((size_t)C * Cb * 2);
    float* psum = (float*)alloc((size_t)C * 4);   // contiguous with pqsm (both 4 KB)
    float* pqsm = (float*)alloc((size_t)C * 4);
    float* mean = (float*)alloc((size_t)C * 4);
    float* istd = (float*)alloc((size_t)C * 4);
    float* rsum = (float*)alloc((size_t)B * N * 4);   // sum-of-exp per attn row
    bf16*  xT   = (bf16*)alloc((size_t)BC * N * C * 2);
    bf16*  g    = (bf16*)alloc((size_t)BC * Cb * N * 2);
    bf16*  attn = (bf16*)alloc((size_t)BC * N * N * 2);
    bf16*  yT   = (bf16*)alloc((size_t)BC * N * Cb * 2);
    bf16*  wyb  = (bf16*)alloc((size_t)BC * C * N * 2);

    // 0) weights f32 -> bf16; zero BN accumulators (psum+pqsm contiguous, 2048 floats)
    f32_to_bf16<<<dim3((Cb * C) / (256 * 4)), 256, 0, stream>>>(Wg, Wgb, Cb * C);
    f32_to_bf16<<<dim3((C * Cb) / (256 * 4)), 256, 0, stream>>>(Wz, Wzb, C * Cb);
    zero_f32<<<dim3(8), 256, 0, stream>>>(psum);

    for (int cs = 0; cs < B; cs += BC) {
        const float* xc = x + (long long)cs * C * N;

        // xT[z][n][c] = x[cs+z][c][n] (bf16)
        transpose_f32_bf16<<<dim3(N / 32, C / 32, BC), dim3(32, 8), 0, stream>>>(xc, xT);

        // g[z][d][n] = sum_c Wgb[d][c] * xT[z][n][c]   (M=512, N=2304, K=1024)
        gemm_btz<false, false, false, false><<<dim3(18 * 4 * BC), 256, 0, stream>>>(
            Wgb, xT, g, C, N, 0, (long long)N * C, (long long)Cb * N, 1.0f,
            nullptr, nullptr, nullptr, 0, 4, BC);

        // attn[z][n][m] = exp(sum_c xT[n][c]*xT[m][c] / 2304), unnormalized, + row sums
        zero_f32<<<dim3(BC * 9), 256, 0, stream>>>(rsum);
        gemm_sym<<<dim3(171, 1, BC), 256, 0, stream>>>(
            xT, attn, C, N, (long long)N * C, (long long)N * N, 1.0f / 2304.0f, rsum);

        // yT[z][n][d] = (1/rsum[z][n]) * sum_m attn[z][n][m] * g[z][d][m]
        // (M=2304, N=512, K=2304); normalization fused into the EPILOGUE
        gemm_btz<false, false, true, true><<<dim3(4 * 18 * BC), 256, 0, stream>>>(
            attn, g, yT, N, Cb, (long long)N * N, (long long)Cb * N, (long long)N * Cb, 1.0f,
            nullptr, nullptr, rsum, N, 4, BC);

        // wy[z][c][n] = sum_d Wzb[c][d] * yT[z][n][d]  (M=1024, N=2304, K=512)
        // -> bf16 into wyb, fused BN sum/sumsq (f32)
        gemm_btz<false, true, false, false><<<dim3(18 * 8 * BC), 256, 0, stream>>>(
            Wzb, yT, wyb, Cb, N, 0, (long long)N * Cb, (long long)C * N, 1.0f,
            psum, pqsm, nullptr, 0, 8, BC);
    }

    // BN: finalize -> apply (+residual)
    bn_finalize<<<dim3(C / 256), 256, 0, stream>>>(psum, pqsm, mean, istd);

    if (BC == B) {
        bn_apply_b<<<dim3((B * C * N) / (256 * 8)), 256, 0, stream>>>(
            wyb, x, gamma, beta, mean, istd, zo);
    } else {
        // BC<8: wyb only holds the LAST chunk's wy. Recompute per chunk with final
        // stats (small-ws fallback; trades extra GEMM time for correctness).
        for (int cs = 0; cs < B; cs += BC) {
            const float* xc = x + (long long)cs * C * N;
            float* zoc = zo + (long long)cs * C * N;
            transpose_f32_bf16<<<dim3(N / 32, C / 32, BC), dim3(32, 8), 0, stream>>>(xc, xT);
            gemm_btz<false, false, false, false><<<dim3(18 * 4 * BC), 256, 0, stream>>>(
                Wgb, xT, g, C, N, 0, (long long)N * C, (long long)Cb * N, 1.0f,
                nullptr, nullptr, nullptr, 0, 4, BC);
            zero_f32<<<dim3(BC * 9), 256, 0, stream>>>(rsum);
            gemm_sym<<<dim3(171, 1, BC), 256, 0, stream>>>(
                xT, attn, C, N, (long long)N * C, (long long)N * N, 1.0f / 2304.0f, rsum);
            gemm_btz<false, false, true, true><<<dim3(4 * 18 * BC), 256, 0, stream>>>(
                attn, g, yT, N, Cb, (long long)N * N, (long long)Cb * N, (long long)N * Cb,
                1.0f, nullptr, nullptr, rsum, N, 4, BC);
            gemm_btz<false, false, false, false><<<dim3(18 * 8 * BC), 256, 0, stream>>>(
                Wzb, yT, wyb, Cb, N, 0, (long long)N * Cb, (long long)C * N, 1.0f,
                nullptr, nullptr, nullptr, 0, 8, BC);
            bn_apply_b<<<dim3((BC * C * N) / (256 * 8)), 256, 0, stream>>>(
                wyb, xc, gamma, beta, mean, istd, zoc);
        }
    }
}

// Round 10
// 380.454 us; speedup vs baseline: 1.0936x; 1.0936x over previous
//
#include <hip/hip_runtime.h>
#include <hip/hip_bf16.h>
#include <stdint.h>

// non_local_layer: B=8, C=1024, N=48*48=2304, Cb=512. f32 in/out, bf16 MFMA inside.
// R18 == R17 resubmitted verbatim (R17 bench died to "container failed twice" -- infra,
// not kernel: source re-audited for OOB/hang/graph-capture hazards, none found; a blind
// mutation would confound the theory test).
// R17: accounting across R13/15/16 shows ~100us of the 416 total is LAUNCH OVERHEAD
// (~11 dispatches x ~10us gap; kernel-time sum is only ~310us), and the y-GEMM SMAX
// epilogue (16 sca regs + scattered rsum loads) regressed y vs plain. Fixes:
// (1) y-GEMM reverted to plain; softmax normalization moved to wy-GEMM B-STAGING
//     (wy's B rows ARE attn rows n; K=512 -> 8 staging iters, 4 VGPRs).
// (2) launches 11 -> 7: one `prep` kernel (both weight converts + zero of contiguous
//     psum|pqsm|rsum), bn_finalize folded into bn_apply.
// gemm_sym untouched (fingerprints: conflicts 0, FETCH ~31MB).

typedef __bf16 bf16;
typedef __attribute__((ext_vector_type(8))) __bf16 bf16x8;
typedef __attribute__((ext_vector_type(4))) __bf16 bf16x4;
typedef __attribute__((ext_vector_type(4))) float f32x4;

// ---------------- GEMM: 128x128 tile, BK=64, 4 waves x (4x4) 16x16x32 MFMA ----------------
// bt-form: D[m][n] = sum_k A[m][k]*B[n][k]; per-z strides sA/sB/sD; D ld=N; alpha scale.
// 1-D grid with z-major XCD affinity: d = blockIdx.x; zz = d % nz; t = d / nz.
// SMAXB: scale B rows by 1/rsum[n] during staging (fused softmax normalization).
// BNRED: accumulate sum/sumsq of D over columns per row (channel) into ps/pq.
template <bool F32OUT, bool BNRED, bool BXI, bool SMAXB>
__global__ __launch_bounds__(256)
void gemm_btz(const bf16* __restrict__ Ag, const bf16* __restrict__ Bg,
              void* __restrict__ Dg, int K, int N,
              long long sA, long long sB, long long sD, float alpha,
              float* __restrict__ ps, float* __restrict__ pq,
              const float* __restrict__ rsum, long long sR, int nInner, int nz)
{
    const int d  = blockIdx.x;
    const int zz = d % nz;
    const int t0 = d / nz;
    const int bI = t0 % nInner;
    const int bO = t0 / nInner;
    const int bx = BXI ? bI : bO;
    const int by = BXI ? bO : bI;

    __shared__ char lds[32768];            // A tile 16 KB + B tile 16 KB
    char* ldsA = lds;
    char* ldsB = lds + 16384;

    const int lane = threadIdx.x & 63;
    const int wv   = threadIdx.x >> 6;     // 4 waves, 2x2 arrangement
    const int wm   = wv >> 1;
    const int wn   = wv & 1;

    const bf16* Ab = Ag + (long long)zz * sA + (long long)by * 128 * K;
    const bf16* Bb = Bg + (long long)zz * sB + (long long)bx * 128 * K;

    // fused-softmax: each staging thread owns 4 fixed B-rows for the whole block
    float binv[4];
    if (SMAXB) {
        #pragma unroll
        for (int t = 0; t < 4; ++t) {
            int row = ((wv * 4 + t) * 64 + lane) >> 3;
            binv[t] = 1.0f / rsum[(long long)zz * sR + bx * 128 + row];
        }
    }

    f32x4 acc[4][4];
    #pragma unroll
    for (int i = 0; i < 4; ++i)
        #pragma unroll
        for (int j = 0; j < 4; ++j) {
            f32x4 z = {0.f, 0.f, 0.f, 0.f};
            acc[i][j] = z;
        }

    for (int k0 = 0; k0 < K; k0 += 64) {
        #pragma unroll
        for (int t = 0; t < 4; ++t) {
            int ch  = (wv * 4 + t) * 64 + lane;   // 0..1023
            int row = ch >> 3;
            int cc  = (ch & 7) ^ (row & 7);
            bf16x8 va = *(const bf16x8*)(Ab + (long long)row * K + k0 + cc * 8);
            bf16x8 vb = *(const bf16x8*)(Bb + (long long)row * K + k0 + cc * 8);
            if (SMAXB) {
                #pragma unroll
                for (int q8 = 0; q8 < 8; ++q8)
                    vb[q8] = (bf16)((float)vb[q8] * binv[t]);
            }
            *(bf16x8*)(ldsA + ch * 16) = va;
            *(bf16x8*)(ldsB + ch * 16) = vb;
        }
        __syncthreads();

        #pragma unroll
        for (int kk = 0; kk < 64; kk += 32) {
            bf16x8 af[4], bfr[4];
            #pragma unroll
            for (int i = 0; i < 4; ++i) {
                int r = wm * 64 + i * 16 + (lane & 15);
                int c = ((kk >> 3) + (lane >> 4)) ^ (r & 7);
                af[i] = *(const bf16x8*)(ldsA + r * 128 + c * 16);
            }
            #pragma unroll
            for (int j = 0; j < 4; ++j) {
                int r = wn * 64 + j * 16 + (lane & 15);
                int c = ((kk >> 3) + (lane >> 4)) ^ (r & 7);
                bfr[j] = *(const bf16x8*)(ldsB + r * 128 + c * 16);
            }
            #pragma unroll
            for (int i = 0; i < 4; ++i)
                #pragma unroll
                for (int j = 0; j < 4; ++j)
                    acc[i][j] = __builtin_amdgcn_mfma_f32_16x16x32_bf16(af[i], bfr[j], acc[i][j], 0, 0, 0);
        }
        __syncthreads();
    }

    float* bs = (float*)lds;               // [128] per-channel sum
    float* bq = (float*)(lds + 512);       // [128] per-channel sumsq
    if (BNRED) {
        if (threadIdx.x < 128) { bs[threadIdx.x] = 0.f; bq[threadIdx.x] = 0.f; }
        __syncthreads();
    }

    const int m_base = by * 128 + wm * 64;
    const int n_base = bx * 128 + wn * 64;
    float s_it[4][4], q_it[4][4];
    #pragma unroll
    for (int i = 0; i < 4; ++i) {
        #pragma unroll
        for (int t = 0; t < 4; ++t) { s_it[i][t] = 0.f; q_it[i][t] = 0.f; }
    }
    #pragma unroll
    for (int i = 0; i < 4; ++i) {
        #pragma unroll
        for (int j = 0; j < 4; ++j) {
            int col = n_base + j * 16 + (lane & 15);
            #pragma unroll
            for (int t = 0; t < 4; ++t) {
                int rowg = m_base + i * 16 + (lane >> 4) * 4 + t;
                float v = acc[i][j][t] * alpha;
                if (F32OUT) ((float*)Dg)[(long long)zz * sD + (long long)rowg * N + col] = v;
                else        ((bf16*)Dg)[(long long)zz * sD + (long long)rowg * N + col] = (bf16)v;
                if (BNRED) { s_it[i][t] += v; q_it[i][t] += v * v; }
            }
        }
    }

    if (BNRED) {
        #pragma unroll
        for (int i = 0; i < 4; ++i) {
            #pragma unroll
            for (int t = 0; t < 4; ++t) {
                float s = s_it[i][t], q = q_it[i][t];
                #pragma unroll
                for (int m = 1; m < 16; m <<= 1) {
                    s += __shfl_xor(s, m);
                    q += __shfl_xor(q, m);
                }
                if ((lane & 15) == 0) {
                    int cl = wm * 64 + i * 16 + (lane >> 4) * 4 + t;   // 0..127
                    atomicAdd(&bs[cl], s);
                    atomicAdd(&bq[cl], q);
                }
            }
        }
        __syncthreads();
        if (threadIdx.x < 128) {
            int cg = by * 128 + threadIdx.x;
            atomicAdd(&ps[cg], bs[threadIdx.x]);
            atomicAdd(&pq[cg], bq[threadIdx.x]);
        }
    }
}

// ---------------- symmetric GEMM: D = exp(alpha * X X^T), upper-tri + sum-of-exp ----------------
// Compact triangular launch with z-major XCD affinity (R12). Stores UNNORMALIZED
// exp(S) (max-free: |S*alpha| <= ~0.5 here) and accumulates per-row sum-of-exp into
// rsum[z][row] via shfl-reduce + atomicAdd. Off-diagonal tiles also mirror the tile
// via LDS transpose (stride 140 = 35 words: odd -> conflict-free, R13/R16-proven) and
// contribute their COLUMN sums to the mirrored rows (exactly-once row coverage).
__global__ __launch_bounds__(256)
void gemm_sym(const bf16* __restrict__ Xg, bf16* __restrict__ Dg,
              int K, int N, long long sX, long long sD, float alpha,
              float* __restrict__ rsum)
{
    const int NZ = gridDim.z;
    const int d  = blockIdx.z * 171 + blockIdx.x;
    const int zz = d % NZ;
    int tlin     = d / NZ;                 // 0..170, bijective (171*NZ blocks total)
    int bi = 0;
    while (tlin >= 18 - bi) { tlin -= 18 - bi; ++bi; }
    const int bj = bi + tlin;
    const bool mir  = (bj > bi);
    const bool diag = (bj == bi);

    __shared__ __align__(16) char lds[35840];   // GEMM: A 16K + B 16K; epilogue: 128 x 140 bf16
    char* ldsA = lds;
    char* ldsB = diag ? lds : (lds + 16384);

    const int lane = threadIdx.x & 63;
    const int wv   = threadIdx.x >> 6;
    const int wm   = wv >> 1;
    const int wn   = wv & 1;

    const bf16* Ab = Xg + (long long)zz * sX + (long long)bi * 128 * K;
    const bf16* Bb = Xg + (long long)zz * sX + (long long)bj * 128 * K;

    f32x4 acc[4][4];
    #pragma unroll
    for (int i = 0; i < 4; ++i)
        #pragma unroll
        for (int j = 0; j < 4; ++j) {
            f32x4 z = {0.f, 0.f, 0.f, 0.f};
            acc[i][j] = z;
        }

    for (int k0 = 0; k0 < K; k0 += 64) {
        #pragma unroll
        for (int t = 0; t < 4; ++t) {
            int ch  = (wv * 4 + t) * 64 + lane;   // 0..1023
            int row = ch >> 3;
            int cc  = (ch & 7) ^ (row & 7);
            bf16x8 va = *(const bf16x8*)(Ab + (long long)row * K + k0 + cc * 8);
            *(bf16x8*)(ldsA + ch * 16) = va;
            if (!diag) {
                bf16x8 vb = *(const bf16x8*)(Bb + (long long)row * K + k0 + cc * 8);
                *(bf16x8*)(ldsB + ch * 16) = vb;
            }
        }
        __syncthreads();

        #pragma unroll
        for (int kk = 0; kk < 64; kk += 32) {
            bf16x8 af[4], bfr[4];
            #pragma unroll
            for (int i = 0; i < 4; ++i) {
                int r = wm * 64 + i * 16 + (lane & 15);
                int c = ((kk >> 3) + (lane >> 4)) ^ (r & 7);
                af[i] = *(const bf16x8*)(ldsA + r * 128 + c * 16);
            }
            #pragma unroll
            for (int j = 0; j < 4; ++j) {
                int r = wn * 64 + j * 16 + (lane & 15);
                int c = ((kk >> 3) + (lane >> 4)) ^ (r & 7);
                bfr[j] = *(const bf16x8*)(ldsB + r * 128 + c * 16);
            }
            #pragma unroll
            for (int i = 0; i < 4; ++i)
                #pragma unroll
                for (int j = 0; j < 4; ++j)
                    acc[i][j] = __builtin_amdgcn_mfma_f32_16x16x32_bf16(af[i], bfr[j], acc[i][j], 0, 0, 0);
        }
        __syncthreads();
    }

    bf16* Db = Dg + (long long)zz * sD;
    float* rs = rsum + (long long)zz * N;
    bf16 (*tr)[140] = (bf16(*)[140])lds;   // k-loop ended with a barrier; LDS free

    float rowsum[4][4];
    float colsum[4];
    #pragma unroll
    for (int i = 0; i < 4; ++i)
        #pragma unroll
        for (int t = 0; t < 4; ++t) rowsum[i][t] = 0.f;
    #pragma unroll
    for (int j = 0; j < 4; ++j) colsum[j] = 0.f;

    #pragma unroll
    for (int i = 0; i < 4; ++i) {
        #pragma unroll
        for (int j = 0; j < 4; ++j) {
            int c_loc = wn * 64 + j * 16 + (lane & 15);
            int col   = bj * 128 + c_loc;
            bf16x4 tv;
            #pragma unroll
            for (int t = 0; t < 4; ++t) {
                int r_loc = wm * 64 + i * 16 + (lane >> 4) * 4 + t;
                float e = __expf(acc[i][j][t] * alpha);
                bf16 eb = (bf16)e;
                Db[(long long)(bi * 128 + r_loc) * N + col] = eb;
                tv[t] = eb;
                rowsum[i][t] += e;
                colsum[j]    += e;
            }
            if (mir) {
                int r_base = wm * 64 + i * 16 + (lane >> 4) * 4;   // 8B-aligned in tr row
                *(bf16x4*)(&tr[c_loc][r_base]) = tv;               // one ds_write_b64
            }
        }
    }

    // row sums: reduce across the 16 col-lanes, one atomicAdd per row
    #pragma unroll
    for (int i = 0; i < 4; ++i) {
        #pragma unroll
        for (int t = 0; t < 4; ++t) {
            float s = rowsum[i][t];
            s += __shfl_xor(s, 1); s += __shfl_xor(s, 2);
            s += __shfl_xor(s, 4); s += __shfl_xor(s, 8);
            if ((lane & 15) == 0)
                atomicAdd(&rs[bi * 128 + wm * 64 + i * 16 + (lane >> 4) * 4 + t], s);
        }
    }
    // col sums -> mirrored rows (off-diagonal only): reduce across the 4 row-lane-groups
    if (mir) {
        #pragma unroll
        for (int j = 0; j < 4; ++j) {
            float s = colsum[j];
            s += __shfl_xor(s, 16); s += __shfl_xor(s, 32);
            if (lane < 16)
                atomicAdd(&rs[bj * 128 + wn * 64 + j * 16 + lane], s);
        }
        __syncthreads();
        // 256 threads x 64 bf16: thread (cc=tid>>1, hf=tid&1) copies half a transposed row.
        const int cc = threadIdx.x >> 1, hf = threadIdx.x & 1;
        const bf16* src = &tr[cc][hf * 64];
        bf16* dst = Db + (long long)(bj * 128 + cc) * N + bi * 128 + hf * 64;
        #pragma unroll
        for (int j2 = 0; j2 < 8; ++j2)
            *(bf16x8*)(dst + j2 * 8) = *(const bf16x8*)(src + j2 * 8);
    }
}

// ---------------- prep: both weight converts + zero of contiguous psum|pqsm|rsum ----------------
// blocks 0..511: Wg -> Wgb; 512..1023: Wz -> Wzb; 1024..1043: zero 20480 floats at zp.
__global__ __launch_bounds__(256)
void prep(const float* __restrict__ Wg, const float* __restrict__ Wz,
          bf16* __restrict__ Wgb, bf16* __restrict__ Wzb, float* __restrict__ zp)
{
    const int b = blockIdx.x;
    if (b < 1024) {
        const float* in = (b < 512) ? Wg : Wz;
        bf16* out       = (b < 512) ? Wgb : Wzb;
        int idx = (((b & 511) * 256) + threadIdx.x) * 4;
        float4 v = *(const float4*)(in + idx);
        out[idx + 0] = (bf16)v.x;
        out[idx + 1] = (bf16)v.y;
        out[idx + 2] = (bf16)v.z;
        out[idx + 3] = (bf16)v.w;
    } else {
        int i = ((b - 1024) * 256 + threadIdx.x) * 4;
        float4 z = {0.f, 0.f, 0.f, 0.f};
        *(float4*)(zp + i) = z;
    }
}

// ---------------- zero-init f32 (BC<8 fallback only) ----------------
__global__ __launch_bounds__(256)
void zero_f32(float* __restrict__ p)
{
    p[blockIdx.x * 256 + threadIdx.x] = 0.f;
}

// ---------------- batched transpose x[z][C][N] (f32) -> xT[z][N][C] (bf16) ----------------
__global__ __launch_bounds__(256)
void transpose_f32_bf16(const float* __restrict__ x, bf16* __restrict__ xT)
{
    __shared__ bf16 tile[32][33];
    const float* xb = x + (long long)blockIdx.z * 1024 * 2304;
    bf16* xo = xT + (long long)blockIdx.z * 2304 * 1024;
    const int n0 = blockIdx.x * 32;
    const int c0 = blockIdx.y * 32;
    const int tx = threadIdx.x, ty = threadIdx.y;   // (32, 8)
    #pragma unroll
    for (int i = 0; i < 32; i += 8)
        tile[ty + i][tx] = (bf16)xb[(long long)(c0 + ty + i) * 2304 + n0 + tx];
    __syncthreads();
    #pragma unroll
    for (int i = 0; i < 32; i += 8)
        xo[(long long)(n0 + ty + i) * 1024 + c0 + tx] = tile[tx][ty + i];
}

// ---------------- BN apply + residual: wy bf16, inline finalize from psum/pqsm ----------------
__global__ __launch_bounds__(256)
void bn_apply_b(const bf16* __restrict__ wy, const float* __restrict__ x,
                const float* __restrict__ gamma, const float* __restrict__ beta,
                const float* __restrict__ ps, const float* __restrict__ pq,
                float* __restrict__ z)
{
    long long idx = ((long long)blockIdx.x * 256 + threadIdx.x) * 8;
    int c = (int)((idx / 2304) & 1023);    // layout [B][C][N]; 8-elem group never crosses c
    float mu = ps[c] * (1.0f / 18432.0f);
    float is = rsqrtf(pq[c] * (1.0f / 18432.0f) - mu * mu + 1e-5f);
    float sc = gamma[c] * is;
    float sh = beta[c] - mu * sc;
    bf16x8 w  = *(const bf16x8*)(wy + idx);
    float4 x0 = *(const float4*)(x + idx);
    float4 x1 = *(const float4*)(x + idx + 4);
    float4 o0, o1;
    o0.x = (float)w[0] * sc + sh + x0.x;
    o0.y = (float)w[1] * sc + sh + x0.y;
    o0.z = (float)w[2] * sc + sh + x0.z;
    o0.w = (float)w[3] * sc + sh + x0.w;
    o1.x = (float)w[4] * sc + sh + x1.x;
    o1.y = (float)w[5] * sc + sh + x1.y;
    o1.z = (float)w[6] * sc + sh + x1.z;
    o1.w = (float)w[7] * sc + sh + x1.w;
    *(float4*)(z + idx)     = o0;
    *(float4*)(z + idx + 4) = o1;
}

extern "C" void kernel_launch(void* const* d_in, const int* in_sizes, int n_in,
                              void* d_out, int out_size, void* d_ws, size_t ws_size,
                              hipStream_t stream)
{
    const float* x     = (const float*)d_in[0];
    const float* Wg    = (const float*)d_in[1];
    const float* Wz    = (const float*)d_in[2];
    const float* gamma = (const float*)d_in[3];
    const float* beta  = (const float*)d_in[4];
    float* zo = (float*)d_out;

    const int B = 8, C = 1024, Cb = 512, N = 2304;

    // ws-adaptive batch chunking: BC in {8,4,2,1}, largest whose footprint fits.
    const size_t fixedB = ((size_t)Cb * C * 2) * 2 + (size_t)C * 4 * 2 + (size_t)B * N * 4 + 4096;
    const size_t perB   = ((size_t)N * C + (size_t)Cb * N + (size_t)N * N + (size_t)N * Cb
                           + (size_t)C * N) * 2 + 1536;
    int BC = 8;
    while (BC > 1 && fixedB + perB * (size_t)BC > ws_size) BC >>= 1;

    char* p = (char*)d_ws;
    auto alloc = [&](size_t bytes) { char* r = p; p += (bytes + 255) & ~(size_t)255; return r; };
    bf16*  Wgb  = (bf16*)alloc((size_t)Cb * C * 2);
    bf16*  Wzb  = (bf16*)alloc((size_t)C * Cb * 2);
    // psum | pqsm | rsum contiguous (4096 + 4096 + 73728 B = 20480 floats, zeroed by prep)
    float* psum = (float*)alloc((size_t)C * 4);
    float* pqsm = (float*)alloc((size_t)C * 4);
    float* rsum = (float*)alloc((size_t)B * N * 4);
    bf16*  xT   = (bf16*)alloc((size_t)BC * N * C * 2);
    bf16*  g    = (bf16*)alloc((size_t)BC * Cb * N * 2);
    bf16*  attn = (bf16*)alloc((size_t)BC * N * N * 2);
    bf16*  yT   = (bf16*)alloc((size_t)BC * N * Cb * 2);
    bf16*  wyb  = (bf16*)alloc((size_t)BC * C * N * 2);

    // 0) one prep launch: weights f32->bf16 + zero psum|pqsm|rsum
    prep<<<dim3(1044), 256, 0, stream>>>(Wg, Wz, Wgb, Wzb, psum);

    for (int cs = 0; cs < B; cs += BC) {
        const float* xc = x + (long long)cs * C * N;

        if (BC < B && cs > 0)   // fallback path: re-zero rsum for this chunk
            zero_f32<<<dim3((BC * N) / 256), 256, 0, stream>>>(rsum);

        // xT[z][n][c] = x[cs+z][c][n] (bf16)
        transpose_f32_bf16<<<dim3(N / 32, C / 32, BC), dim3(32, 8), 0, stream>>>(xc, xT);

        // g[z][d][n] = sum_c Wgb[d][c] * xT[z][n][c]   (M=512, N=2304, K=1024)
        gemm_btz<false, false, false, false><<<dim3(18 * 4 * BC), 256, 0, stream>>>(
            Wgb, xT, g, C, N, 0, (long long)N * C, (long long)Cb * N, 1.0f,
            nullptr, nullptr, nullptr, 0, 4, BC);

        // attn[z][n][m] = exp(sum_c xT[n][c]*xT[m][c] / 2304), unnormalized, + row sums
        gemm_sym<<<dim3(171, 1, BC), 256, 0, stream>>>(
            xT, attn, C, N, (long long)N * C, (long long)N * N, 1.0f / 2304.0f, rsum);

        // yT[z][n][d] = sum_m attn[z][n][m] * g[z][d][m]  (M=2304, N=512, K=2304), plain
        gemm_btz<false, false, true, false><<<dim3(4 * 18 * BC), 256, 0, stream>>>(
            attn, g, yT, N, Cb, (long long)N * N, (long long)Cb * N, (long long)N * Cb, 1.0f,
            nullptr, nullptr, nullptr, 0, 4, BC);

        // wy[z][c][n] = sum_d Wzb[c][d] * (yT[z][n][d]/rsum[z][n])  (M=1024, N=2304, K=512)
        // softmax normalization fused into B-staging; bf16 out; fused BN sum/sumsq
        gemm_btz<false, true, false, true><<<dim3(18 * 8 * BC), 256, 0, stream>>>(
            Wzb, yT, wyb, Cb, N, 0, (long long)N * Cb, (long long)C * N, 1.0f,
            psum, pqsm, rsum, N, 8, BC);
    }

    if (BC == B) {
        // BN apply + residual (mean/istd inline from psum/pqsm)
        bn_apply_b<<<dim3((B * C * N) / (256 * 8)), 256, 0, stream>>>(
            wyb, x, gamma, beta, psum, pqsm, zo);
    } else {
        // BC<8: wyb only holds the LAST chunk's wy. Recompute per chunk with final
        // stats (small-ws fallback; trades extra GEMM time for correctness).
        for (int cs = 0; cs < B; cs += BC) {
            const float* xc = x + (long long)cs * C * N;
            float* zoc = zo + (long long)cs * C * N;
            zero_f32<<<dim3((BC * N) / 256), 256, 0, stream>>>(rsum);
            transpose_f32_bf16<<<dim3(N / 32, C / 32, BC), dim3(32, 8), 0, stream>>>(xc, xT);
            gemm_btz<false, false, false, false><<<dim3(18 * 4 * BC), 256, 0, stream>>>(
                Wgb, xT, g, C, N, 0, (long long)N * C, (long long)Cb * N, 1.0f,
                nullptr, nullptr, nullptr, 0, 4, BC);
            gemm_sym<<<dim3(171, 1, BC), 256, 0, stream>>>(
                xT, attn, C, N, (long long)N * C, (long long)N * N, 1.0f / 2304.0f, rsum);
            gemm_btz<false, false, true, false><<<dim3(4 * 18 * BC), 256, 0, stream>>>(
                attn, g, yT, N, Cb, (long long)N * N, (long long)Cb * N, (long long)N * Cb,
                1.0f, nullptr, nullptr, nullptr, 0, 4, BC);
            gemm_btz<false, false, false, true><<<dim3(18 * 8 * BC), 256, 0, stream>>>(
                Wzb, yT, wyb, Cb, N, 0, (long long)N * Cb, (long long)C * N, 1.0f,
                nullptr, nullptr, rsum, N, 8, BC);
            bn_apply_b<<<dim3((BC * C * N) / (256 * 8)), 256, 0, stream>>>(
                wyb, xc, gamma, beta, psum, pqsm, zoc);
        }
    }
}